// Round 1
// 285.096 us; speedup vs baseline: 1.0129x; 1.0129x over previous
//
#include <hip/hip_runtime.h>
#include <cmath>

// ---------------------------------------------------------------------------
// min_max_net: w' = weight with montn columns squared; y = x @ w'^T + bias;
// out[b] = (rand_u[b] < sigmoid(max_g min_{j in g} y[b, g*64+j])) ? 1 : 0
//
// R10: GEMM rebuilt as 256x256 / BK=64 / 8-wave (2Mx4N) 4-phase schedule with
// counted vmcnt (T3+T4), setprio around MFMA clusters (T5), XOR-swizzled LDS
// (T2, zero conflicts), half-tile global_load_lds prefetch 7 halves ahead,
// vmcnt(6) once per K-tile (drain only at tail). Race protocol: every LDS
// region's reads complete (lgkmcnt(0) pre-barrier) strictly before the phase
// that issues its overwrite; wm==0 waves front-load all A reads (their half
// is re-staged first). XCD n-slice swizzle kept (2MB W slab per XCD L2).
// Convert / finalize / recompute / decide unchanged from R9.
// ---------------------------------------------------------------------------

typedef _Float16 f16x8 __attribute__((ext_vector_type(8)));
typedef float f32x4 __attribute__((ext_vector_type(4)));

#define MARGIN_EPS 4e-3f
#define MAX_UNDEC 96

__device__ __forceinline__ void async_load16(const void* gptr, void* lptr) {
  __builtin_amdgcn_global_load_lds(
      (const __attribute__((address_space(1))) void*)gptr,
      (__attribute__((address_space(3))) void*)lptr, 16, 0, 0);
}

__device__ __forceinline__ float us2f(unsigned short u) {
  return (float)__builtin_bit_cast(_Float16, u);
}

// ---- kernel 1: in-place fp32 row -> [hi fp16 | lo fp16], 1 wave per row ----
__global__ void convert_split(float* __restrict__ x, float* __restrict__ wgt,
                              const int* __restrict__ montn,
                              int* __restrict__ count) {
  __shared__ unsigned msk[64];
  const int t = threadIdx.x, l = t & 63, w = t >> 6;
  const int r = blockIdx.x * 4 + w;
  const int use_mask = (r >= 8192) ? 1 : 0;   // block-uniform (4-row blocks)
  if (blockIdx.x == 0 && t == 0) *count = 0;
  if (use_mask) {
    if (t < 64) msk[t] = 0u;
    __syncthreads();
    for (int j = t; j < 512; j += 256) {
      const int c = montn[j];
      atomicOr(&msk[c >> 5], 1u << (c & 31));
    }
    __syncthreads();
  }
  float* rowp = use_mask ? (wgt + (size_t)(r - 8192) * 2048)
                         : (x + (size_t)r * 2048);
  float4 v[4][2];
#pragma unroll
  for (int p = 0; p < 4; ++p) {
    v[p][0] = ((const float4*)rowp)[p * 128 + 2 * l];
    v[p][1] = ((const float4*)rowp)[p * 128 + 2 * l + 1];
  }
  unsigned mw[4];
#pragma unroll
  for (int p = 0; p < 4; ++p)
    mw[p] = use_mask ? msk[p * 16 + (l >> 2)] : 0u;

  unsigned short* up = (unsigned short*)rowp;
#pragma unroll
  for (int p = 0; p < 4; ++p) {
    float f[8];
    f[0] = v[p][0].x; f[1] = v[p][0].y; f[2] = v[p][0].z; f[3] = v[p][0].w;
    f[4] = v[p][1].x; f[5] = v[p][1].y; f[6] = v[p][1].z; f[7] = v[p][1].w;
    unsigned short hs[8], ls[8];
#pragma unroll
    for (int c = 0; c < 8; ++c) {
      float g = f[c];
      if ((mw[p] >> (8 * (l & 3) + c)) & 1u) g = g * g;
      _Float16 h = (_Float16)g;          // RTNE
      float res = g - (float)h;          // exact in fp32
      _Float16 lo = (_Float16)res;
      hs[c] = __builtin_bit_cast(unsigned short, h);
      ls[c] = __builtin_bit_cast(unsigned short, lo);
    }
    uint4 H, L;
    H.x = (unsigned)hs[0] | ((unsigned)hs[1] << 16);
    H.y = (unsigned)hs[2] | ((unsigned)hs[3] << 16);
    H.z = (unsigned)hs[4] | ((unsigned)hs[5] << 16);
    H.w = (unsigned)hs[6] | ((unsigned)hs[7] << 16);
    L.x = (unsigned)ls[0] | ((unsigned)ls[1] << 16);
    L.y = (unsigned)ls[2] | ((unsigned)ls[3] << 16);
    L.z = (unsigned)ls[4] | ((unsigned)ls[5] << 16);
    L.w = (unsigned)ls[6] | ((unsigned)ls[7] << 16);
    *((uint4*)(up + p * 512 + 8 * l)) = H;            // hi plane [0,2048)
    *((uint4*)(up + 2048 + p * 512 + 8 * l)) = L;     // lo plane [2048,4096)
  }
}

// ---- kernel 2: hi*hi GEMM + fused bias/group-min ---------------------------
// 256x256 tile, BK=64, 8 waves (2Mx4N), wave tile 128x64 = one output group.
// 4 phases per K-tile, one C-quadrant (16 MFMA) per phase; half-tile
// global_load_lds prefetch with stage(h)=phase+7; vmcnt(6) once per K-tile.
#define SBAR() __builtin_amdgcn_sched_barrier(0)
#define BARR() __builtin_amdgcn_s_barrier()
#define LGKM0() asm volatile("s_waitcnt lgkmcnt(0)" ::: "memory")

__global__ __launch_bounds__(512, 2) void gemm_minmax(
    const unsigned short* __restrict__ X, const unsigned short* __restrict__ W,
    const float* __restrict__ bias, float* __restrict__ gmins) {
  __shared__ unsigned short As[2 * 256 * 64];   // 64 KB (double-buffered A)
  __shared__ unsigned short Bs[2 * 256 * 64];   // 64 KB (double-buffered B)
  const int t = threadIdx.x;
  const int lane = t & 63;
  const int w = t >> 6;            // 0..7
  const int wm = w >> 2;           // 0..1 : 128-row half
  const int wn = w & 3;            // 0..3 : 64-col group
  const int lin = blockIdx.x;      // 512 blocks = 32 m x 16 n
  const int m0 = (lin >> 4) * 256;
  const int n0 = (((lin & 7) << 1) + ((lin >> 3) & 1)) * 256;  // XCD n-slice

  // staging geometry: call covers 64 rows (8 waves x 8 rows); lane row =
  // w*8+(l>>3), stored chunk l&7 holds global chunk (l&7)^(row&7).
  const int rowBase = w * 8 + (lane >> 3);
  const int gchunk = ((lane & 7) ^ ((lane >> 3) & 7)) * 8;   // ushort offset
  const size_t gA0 = (size_t)(m0 + rowBase) * 4096 + gchunk;
  const size_t gB0 = (size_t)(n0 + rowBase) * 4096 + gchunk;
  const int w8row = w * 8;

  const int am = lane & 15, quad = lane >> 4;
  int arow[8], brw[4], swz[2];
#pragma unroll
  for (int i = 0; i < 8; ++i) arow[i] = (wm * 128 + i * 16 + am) * 64;
#pragma unroll
  for (int j = 0; j < 4; ++j) brw[j] = (wn * 64 + j * 16 + am) * 64;
#pragma unroll
  for (int h = 0; h < 2; ++h) swz[h] = (((h << 2) + quad) ^ (am & 7)) * 8;

  f32x4 acc[8][4];
#pragma unroll
  for (int i = 0; i < 8; ++i)
#pragma unroll
    for (int j = 0; j < 4; ++j) acc[i][j] = (f32x4){0.f, 0.f, 0.f, 0.f};
  f16x8 av[8][2];   // all A frags for the tile (wm's half)
  f16x8 bv[2][2];   // B frag pair, reused j01 -> j23

  // stage half-tile h: tile=h>>2, part 0/1 = A half0/1, 2/3 = B half0/1.
  // 2 x global_load_lds(16B) per thread per call.
  auto STAGE = [&](int h) {
    if (h >= 128) return;
    const int tile = h >> 2, part = h & 3;
    const int bufo = (tile & 1) << 14;           // ushort offset 16384
    const size_t koff = (size_t)(tile << 6);
    if (part < 2) {
#pragma unroll
      for (int c = 0; c < 2; ++c) {
        const int r0 = part * 128 + c * 64;
        async_load16(X + gA0 + (size_t)r0 * 4096 + koff,
                     As + bufo + (r0 + w8row) * 64);
      }
    } else {
#pragma unroll
      for (int c = 0; c < 2; ++c) {
        const int r0 = (part - 2) * 128 + c * 64;
        async_load16(W + gB0 + (size_t)r0 * 4096 + koff,
                     Bs + bufo + (r0 + w8row) * 64);
      }
    }
  };

  // prologue: stage halves 0..6 (tile0 + 3 halves of tile1); tile0 landed.
#pragma unroll
  for (int h = 0; h < 7; ++h) STAGE(h);
  asm volatile("s_waitcnt vmcnt(6)" ::: "memory");
  SBAR(); BARR(); SBAR();

#pragma unroll 2
  for (int kt = 0; kt < 32; ++kt) {
    const int bufo = (kt & 1) << 14;
    // -------- phase 0: quadrant (mb 0..3, j 0..1) --------
    {
#pragma unroll
      for (int i = 0; i < 4; ++i)
#pragma unroll
        for (int kk = 0; kk < 2; ++kk)
          av[i][kk] = *(const f16x8*)(As + bufo + arow[i] + swz[kk]);
      if (wm == 0) {   // wm0's A-half is re-staged at phase 1: read ALL now
#pragma unroll
        for (int i = 4; i < 8; ++i)
#pragma unroll
          for (int kk = 0; kk < 2; ++kk)
            av[i][kk] = *(const f16x8*)(As + bufo + arow[i] + swz[kk]);
      }
#pragma unroll
      for (int j = 0; j < 2; ++j)
#pragma unroll
        for (int kk = 0; kk < 2; ++kk)
          bv[j][kk] = *(const f16x8*)(Bs + bufo + brw[j] + swz[kk]);
      STAGE(4 * kt + 7);
      SBAR(); BARR(); LGKM0(); SBAR();
      __builtin_amdgcn_s_setprio(1);
#pragma unroll
      for (int mb = 0; mb < 4; ++mb)
#pragma unroll
        for (int j = 0; j < 2; ++j)
#pragma unroll
          for (int kk = 0; kk < 2; ++kk)
            acc[mb][j] = __builtin_amdgcn_mfma_f32_16x16x32_f16(
                av[mb][kk], bv[j][kk], acc[mb][j], 0, 0, 0);
      __builtin_amdgcn_s_setprio(0);
      SBAR(); BARR(); SBAR();
    }
    // -------- phase 1: quadrant (mb 4..7, j 0..1) --------
    {
      if (wm == 1) {   // wm1's half is re-staged at phase 2: finish A reads
#pragma unroll
        for (int i = 4; i < 8; ++i)
#pragma unroll
          for (int kk = 0; kk < 2; ++kk)
            av[i][kk] = *(const f16x8*)(As + bufo + arow[i] + swz[kk]);
      }
      STAGE(4 * kt + 8);
      SBAR(); BARR(); LGKM0(); SBAR();
      __builtin_amdgcn_s_setprio(1);
#pragma unroll
      for (int mb = 4; mb < 8; ++mb)
#pragma unroll
        for (int j = 0; j < 2; ++j)
#pragma unroll
          for (int kk = 0; kk < 2; ++kk)
            acc[mb][j] = __builtin_amdgcn_mfma_f32_16x16x32_f16(
                av[mb][kk], bv[j][kk], acc[mb][j], 0, 0, 0);
      __builtin_amdgcn_s_setprio(0);
      SBAR(); BARR(); SBAR();
    }
    // -------- phase 2: quadrant (mb 0..3, j 2..3) --------
    {
#pragma unroll
      for (int j = 0; j < 2; ++j)
#pragma unroll
        for (int kk = 0; kk < 2; ++kk)
          bv[j][kk] = *(const f16x8*)(Bs + bufo + brw[2 + j] + swz[kk]);
      STAGE(4 * kt + 9);
      SBAR(); BARR(); LGKM0(); SBAR();
      __builtin_amdgcn_s_setprio(1);
#pragma unroll
      for (int mb = 0; mb < 4; ++mb)
#pragma unroll
        for (int j = 0; j < 2; ++j)
#pragma unroll
          for (int kk = 0; kk < 2; ++kk)
            acc[mb][2 + j] = __builtin_amdgcn_mfma_f32_16x16x32_f16(
                av[mb][kk], bv[j][kk], acc[mb][2 + j], 0, 0, 0);
      __builtin_amdgcn_s_setprio(0);
      SBAR(); BARR(); SBAR();
    }
    // -------- phase 3: quadrant (mb 4..7, j 2..3) --------
    {
      STAGE(4 * kt + 10);
      SBAR(); BARR(); SBAR();
      __builtin_amdgcn_s_setprio(1);
#pragma unroll
      for (int mb = 4; mb < 8; ++mb)
#pragma unroll
        for (int j = 0; j < 2; ++j)
#pragma unroll
          for (int kk = 0; kk < 2; ++kk)
            acc[mb][2 + j] = __builtin_amdgcn_mfma_f32_16x16x32_f16(
                av[mb][kk], bv[j][kk], acc[mb][2 + j], 0, 0, 0);
      __builtin_amdgcn_s_setprio(0);
      SBAR();
      if (kt < 30) {
        asm volatile("s_waitcnt vmcnt(6)" ::: "memory");   // 3 halves in flight
      } else if (kt == 30) {
        asm volatile("s_waitcnt vmcnt(0)" ::: "memory");   // tail drain
      }
      BARR(); SBAR();
    }
  }

  // epilogue: bias + per-group (64-col) min; wave covers exactly 1 group.
  const int grp = (n0 >> 6) + wn;
  float bj[4];
#pragma unroll
  for (int j = 0; j < 4; ++j) bj[j] = bias[n0 + wn * 64 + j * 16 + am];
#pragma unroll
  for (int mb = 0; mb < 8; ++mb) {
#pragma unroll
    for (int reg = 0; reg < 4; ++reg) {
      float v = fminf(fminf(acc[mb][0][reg] + bj[0], acc[mb][1][reg] + bj[1]),
                      fminf(acc[mb][2][reg] + bj[2], acc[mb][3][reg] + bj[3]));
      v = fminf(v, __shfl_xor(v, 1, 64));
      v = fminf(v, __shfl_xor(v, 2, 64));
      v = fminf(v, __shfl_xor(v, 4, 64));
      v = fminf(v, __shfl_xor(v, 8, 64));
      if (am == 0) {
        const int row = m0 + wm * 128 + mb * 16 + quad * 4 + reg;
        gmins[(size_t)row * 64 + grp] = v;
      }
    }
  }
}

// ---- kernel 3: max over groups -> margin test (+ ybuf zeroing) -------------
__global__ void finalize_margin(const float* __restrict__ gmins,
                                const float* __restrict__ rand_u,
                                float* __restrict__ out,
                                int* __restrict__ count, int* __restrict__ undec,
                                float4* __restrict__ ybuf4) {
  if (blockIdx.x < 384)  // zero ybuf: 384*256 float4 = 96*4096 floats
    ybuf4[(size_t)blockIdx.x * 256 + threadIdx.x] = (float4){0.f, 0.f, 0.f, 0.f};
  const int wv = threadIdx.x >> 6, lane = threadIdx.x & 63;
  const int row = blockIdx.x * 4 + wv;
  float v = gmins[(size_t)row * 64 + lane];
  v = fmaxf(v, __shfl_xor(v, 1, 64));
  v = fmaxf(v, __shfl_xor(v, 2, 64));
  v = fmaxf(v, __shfl_xor(v, 4, 64));
  v = fmaxf(v, __shfl_xor(v, 8, 64));
  v = fmaxf(v, __shfl_xor(v, 16, 64));
  v = fmaxf(v, __shfl_xor(v, 32, 64));
  if (lane == 0) {
    const float u = rand_u[row];
    const float slo = 1.0f / (1.0f + expf(-(v - MARGIN_EPS)));
    const float shi = 1.0f / (1.0f + expf(-(v + MARGIN_EPS)));
    if (u < slo) {
      out[row] = 1.0f;
    } else if (u >= shi) {
      out[row] = 0.0f;
    } else {
      const int i = atomicAdd(count, 1);
      if (i < 8192) undec[i] = row;
    }
  }
}

// ---- kernel 4: exact fp32 recompute, W read ONCE ---------------------------
__global__ __launch_bounds__(256) void recompute_rows(
    const unsigned short* __restrict__ X, const unsigned short* __restrict__ W,
    const int* __restrict__ count, const int* __restrict__ undec,
    float* __restrict__ ybuf) {
  __shared__ float wf[64 * 129];   // ~33 KB
  __shared__ float part[256];
  const int g = blockIdx.x, kc = blockIdx.y;
  const int t = threadIdx.x;
  int n = *count;
  if (n > MAX_UNDEC) n = MAX_UNDEC;
  if (n == 0) return;

  {  // stage: thread t -> col t>>2, k-segment t&3 (32 k each)
    const int cl = t >> 2, ks = t & 3;
    const unsigned short* wp =
        W + (size_t)(g * 64 + cl) * 4096 + kc * 128 + ks * 32;
    float* dst = wf + cl * 129 + ks * 32;
#pragma unroll
    for (int i = 0; i < 32; i += 8) {
      uint4 hv = *(const uint4*)(wp + i);
      uint4 lv = *(const uint4*)(wp + 2048 + i);
      const unsigned* hw = (const unsigned*)&hv;
      const unsigned* lw = (const unsigned*)&lv;
#pragma unroll
      for (int m = 0; m < 4; ++m) {
        dst[i + 2 * m] = us2f((unsigned short)(hw[m] & 0xFFFF)) +
                         us2f((unsigned short)(lw[m] & 0xFFFF));
        dst[i + 2 * m + 1] = us2f((unsigned short)(hw[m] >> 16)) +
                             us2f((unsigned short)(lw[m] >> 16));
      }
    }
  }
  __syncthreads();

  const int col = t & 63, kq = t >> 6;   // 32 k per quarter
  const float* wcol = wf + col * 129 + kq * 32;
  for (int s = 0; s < n; ++s) {
    const int row = undec[s];
    const unsigned short* xp = X + (size_t)row * 4096 + kc * 128 + kq * 32;
    float acc = 0.f;
#pragma unroll
    for (int i = 0; i < 32; i += 8) {
      uint4 hv = *(const uint4*)(xp + i);
      uint4 lv = *(const uint4*)(xp + 2048 + i);
      const unsigned* hw = (const unsigned*)&hv;
      const unsigned* lw = (const unsigned*)&lv;
#pragma unroll
      for (int m = 0; m < 4; ++m) {
        const float x0 = us2f((unsigned short)(hw[m] & 0xFFFF)) +
                         us2f((unsigned short)(lw[m] & 0xFFFF));
        const float x1 = us2f((unsigned short)(hw[m] >> 16)) +
                         us2f((unsigned short)(lw[m] >> 16));
        acc = fmaf(x0, wcol[i + 2 * m], acc);
        acc = fmaf(x1, wcol[i + 2 * m + 1], acc);
      }
    }
    part[t] = acc;
    __syncthreads();
    if (t < 64) {
      const float y = part[t] + part[t + 64] + part[t + 128] + part[t + 192];
      atomicAdd(ybuf + (size_t)s * 4096 + g * 64 + t, y);
    }
    __syncthreads();
  }
}

// ---- kernel 5: final decision for undecided rows ---------------------------
__global__ void decide(const float* __restrict__ ybuf,
                       const int* __restrict__ undec, const int* __restrict__ count,
                       const float* __restrict__ bias,
                       const float* __restrict__ rand_u, float* __restrict__ out) {
  __shared__ float gm[64];
  int n = *count;
  if (n > MAX_UNDEC) n = MAX_UNDEC;
  const int s = blockIdx.x;
  if (s >= n) return;
  const int t = threadIdx.x;
  const int g = t >> 2, p4 = t & 3;
  const float* yb = ybuf + (size_t)s * 4096;
  const int c0 = g * 64 + p4 * 16;
  float m = 3.4e38f;
#pragma unroll
  for (int e = 0; e < 16; ++e) m = fminf(m, yb[c0 + e] + bias[c0 + e]);
  m = fminf(m, __shfl_xor(m, 1, 64));
  m = fminf(m, __shfl_xor(m, 2, 64));
  if (p4 == 0) gm[g] = m;
  __syncthreads();
  if (t < 64) {
    float v = gm[t];
    v = fmaxf(v, __shfl_xor(v, 1, 64));
    v = fmaxf(v, __shfl_xor(v, 2, 64));
    v = fmaxf(v, __shfl_xor(v, 4, 64));
    v = fmaxf(v, __shfl_xor(v, 8, 64));
    v = fmaxf(v, __shfl_xor(v, 16, 64));
    v = fmaxf(v, __shfl_xor(v, 32, 64));
    if (t == 0) {
      const int row = undec[s];
      const float sg = 1.0f / (1.0f + expf(-v));
      out[row] = (rand_u[row] < sg) ? 1.0f : 0.0f;
    }
  }
}

extern "C" void kernel_launch(void* const* d_in, const int* in_sizes, int n_in,
                              void* d_out, int out_size, void* d_ws, size_t ws_size,
                              hipStream_t stream) {
  float* x = (float*)d_in[0];           // [8192, 2048] fp32 (mutated in place)
  float* weight = (float*)d_in[1];      // [4096, 2048] fp32 (mutated in place)
  const float* bias = (const float*)d_in[2];
  const float* rand_u = (const float*)d_in[3];
  const int* montn = (const int*)d_in[4];
  float* out = (float*)d_out;

  char* ws = (char*)d_ws;
  int* count = (int*)ws;                         // 4 B
  int* undec = (int*)(ws + 256);                 // 32 KB
  float* ybuf = (float*)(ws + 65536);            // 96*4096*4 = 1.5 MB
  float* gmins = (float*)(ws + 65536 + 1572864); // 2 MB

  convert_split<<<3072, 256, 0, stream>>>(x, weight, montn, count);
  gemm_minmax<<<512, 512, 0, stream>>>(
      (const unsigned short*)x, (const unsigned short*)weight, bias, gmins);
  finalize_margin<<<2048, 256, 0, stream>>>(gmins, rand_u, out, count, undec,
                                            (float4*)ybuf);
  recompute_rows<<<dim3(64, 16), 256, 0, stream>>>(
      (const unsigned short*)x, (const unsigned short*)weight, count, undec, ybuf);
  decide<<<MAX_UNDEC, 256, 0, stream>>>(ybuf, undec, count, bias, rand_u, out);
}